// Round 1
// 869.505 us; speedup vs baseline: 1.0177x; 1.0177x over previous
//
#include <hip/hip_runtime.h>

// MHA: B=2, S=2048, HID=1024, H=16, DK=64. SCALE=1/8, NEG=-1e9.
// Pipeline: [cvt qkv fp32->bf16] + [wtrans z=4] -> [fused qkv gemm, 128x128,
//           async16 both operands] -> [flash attn q128, bias reg-prefetch]
//           -> [out gemm 64x128].
// bf16 MFMA 16x16x32; A[m=lane&15][k=quad*8+j], B^T[n=lane&15][k=quad*8+j],
// C/D col=lane&15, row=quad*4+reg.
// LDS tiles: unpadded 64-u16 rows, XOR group swizzle (g ^= row&7) -> conflict-free
// frag reads AND global_load_lds-compatible (lane-linear LDS writes; swizzle applied
// to the global gather address).
// Grids are flat 1D with XCD-aware decode (XCD = wgid % 8 round-robin): blocks
// sharing an A-panel (GEMMs) or a K/V panel (attn) are placed 8-stride apart so
// they co-reside on one XCD's L2.

typedef __bf16 bf16x8 __attribute__((ext_vector_type(8)));
typedef float f32x4 __attribute__((ext_vector_type(4)));
typedef unsigned short u16x8 __attribute__((ext_vector_type(8)));

#define NEGV (-1000000000.0f)

typedef __attribute__((address_space(3))) unsigned int lds_u32;
typedef const __attribute__((address_space(1))) unsigned int glb_u32;

static __device__ __forceinline__ void async16(const void* g, void* l) {
  __builtin_amdgcn_global_load_lds((glb_u32*)g, (lds_u32*)l, 16, 0, 0);
}

static __device__ __forceinline__ unsigned short f2b(float f) {
  unsigned int u = __float_as_uint(f);
  return (unsigned short)((u + 0x7FFFu + ((u >> 16) & 1u)) >> 16);
}

static __device__ __forceinline__ bf16x8 ld8(const unsigned short* p) {
  return __builtin_bit_cast(bf16x8, *(const u16x8*)p);
}

// ---- elementwise fp32 -> bf16 for q,k,v (removes in-GEMM conversion + 8x fp32 re-reads) ----
__global__ __launch_bounds__(256) void k_cvt(const float* __restrict__ A0, const float* __restrict__ A1,
                                             const float* __restrict__ A2,
                                             unsigned short* __restrict__ O0, unsigned short* __restrict__ O1,
                                             unsigned short* __restrict__ O2) {
  const float* A = (blockIdx.z == 0) ? A0 : (blockIdx.z == 1) ? A1 : A2;
  unsigned short* O = (blockIdx.z == 0) ? O0 : (blockIdx.z == 1) ? O1 : O2;
  size_t i = ((size_t)blockIdx.x * 256 + threadIdx.x) * 8;
  float4 f0 = *(const float4*)(A + i);
  float4 f1 = *(const float4*)(A + i + 4);
  u16x8 h;
  h[0] = f2b(f0.x); h[1] = f2b(f0.y); h[2] = f2b(f0.z); h[3] = f2b(f0.w);
  h[4] = f2b(f1.x); h[5] = f2b(f1.y); h[6] = f2b(f1.z); h[7] = f2b(f1.w);
  *(u16x8*)(O + i) = h;
}

// ---- transpose 1024x1024 fp32 W -> bf16 W^T (N x K), batched over z ----
__global__ __launch_bounds__(256) void k_wtrans(const float* __restrict__ W0, const float* __restrict__ W1,
                                                const float* __restrict__ W2, const float* __restrict__ W3,
                                                unsigned short* __restrict__ T0, unsigned short* __restrict__ T1,
                                                unsigned short* __restrict__ T2, unsigned short* __restrict__ T3) {
  const float* W = (blockIdx.z == 0) ? W0 : (blockIdx.z == 1) ? W1 : (blockIdx.z == 2) ? W2 : W3;
  unsigned short* Wt = (blockIdx.z == 0) ? T0 : (blockIdx.z == 1) ? T1 : (blockIdx.z == 2) ? T2 : T3;
  __shared__ float tile[32][33];
  int k0 = blockIdx.x * 32, n0 = blockIdx.y * 32;
  int tx = threadIdx.x, ty = threadIdx.y;
  #pragma unroll
  for (int i = 0; i < 32; i += 8)
    tile[ty + i][tx] = W[(size_t)(k0 + ty + i) * 1024 + n0 + tx];
  __syncthreads();
  #pragma unroll
  for (int i = 0; i < 32; i += 8)
    Wt[(size_t)(n0 + ty + i) * 1024 + k0 + tx] = f2b(tile[tx][ty + i]);
}

// ---- fused QKV GEMM: Y(4096x1024) = A(bf16) @ Wt^T + bias, 128x128 tile ----
// flat grid 768: mode = f>>8; r = f&255; m_t = r&31 (XCD key), n_t = r>>5.
// The 8 n-blocks sharing an A-panel have equal r%8 -> same XCD -> A L2-resident.
// mode 0: A=q, out=qh bf16 (B,H,S,DK) scaled 1/8
// mode 1: A=k, out=kh bf16 (B,H,S,DK)
// mode 2: A=v, out=vt bf16 (B,H,DK,S)  (transposed epilogue)
__global__ __launch_bounds__(256) void k_gemm_qkv(
    const unsigned short* __restrict__ A0, const unsigned short* __restrict__ A1,
    const unsigned short* __restrict__ A2,
    const unsigned short* __restrict__ W0, const unsigned short* __restrict__ W1,
    const unsigned short* __restrict__ W2,
    const float* __restrict__ b0, const float* __restrict__ b1, const float* __restrict__ b2,
    unsigned short* __restrict__ o0, unsigned short* __restrict__ o1, unsigned short* __restrict__ o2) {
  int f = blockIdx.x;
  int mode = f >> 8;
  int r = f & 255;
  int m0 = (r & 31) * 128, n0 = (r >> 5) * 128;
  const unsigned short* Ab = (mode == 0) ? A0 : (mode == 1) ? A1 : A2;
  const unsigned short* Bt = (mode == 0) ? W0 : (mode == 1) ? W1 : W2;
  const float* bias = (mode == 0) ? b0 : (mode == 1) ? b1 : b2;
  unsigned short* outb = (mode == 0) ? o0 : (mode == 1) ? o1 : o2;

  __shared__ __align__(16) unsigned short smem[128 * 136];  // stage + epilogue union
  unsigned short* As = smem;             // [128][64], swizzled groups
  unsigned short* Bs = smem + 128 * 64;  // [128][64], swizzled groups
  int t = threadIdx.x;
  int wave = t >> 6, lane = t & 63;
  int r16 = lane & 15, quad = lane >> 4;
  int wm = (wave >> 1) * 64, wn = (wave & 1) * 64;
  f32x4 acc[4][4] = {};

  for (int k0 = 0; k0 < 1024; k0 += 64) {
    __syncthreads();
    #pragma unroll
    for (int i = 0; i < 4; i++) {  // both operands via async copy, swizzled gather
      int row = wave * 32 + i * 8 + (lane >> 3);
      int sw = (((lane & 7) ^ (row & 7))) * 8;
      async16(Ab + (size_t)(m0 + row) * 1024 + k0 + sw, &As[(wave * 32 + i * 8) * 64]);
      async16(Bt + (size_t)(n0 + row) * 1024 + k0 + sw, &Bs[(wave * 32 + i * 8) * 64]);
    }
    __syncthreads();
    #pragma unroll
    for (int kk2 = 0; kk2 < 2; kk2++) {
      bf16x8 av[4], bv[4];
      int gq = quad + kk2 * 4;
      #pragma unroll
      for (int mt = 0; mt < 4; mt++) {
        int lm = wm + mt * 16 + r16;
        av[mt] = ld8(&As[lm * 64 + (gq ^ (lm & 7)) * 8]);
      }
      #pragma unroll
      for (int nt = 0; nt < 4; nt++) {
        int ln = wn + nt * 16 + r16;
        bv[nt] = ld8(&Bs[ln * 64 + (gq ^ (ln & 7)) * 8]);
      }
      #pragma unroll
      for (int mt = 0; mt < 4; mt++)
        #pragma unroll
        for (int nt = 0; nt < 4; nt++)
          acc[mt][nt] = __builtin_amdgcn_mfma_f32_16x16x32_bf16(av[mt], bv[nt], acc[mt][nt], 0, 0, 0);
    }
  }

  __syncthreads();  // staging reads done; smem becomes epilogue buffer [128][136]
  float scale = (mode == 0) ? 0.125f : 1.0f;
  #pragma unroll
  for (int nt = 0; nt < 4; nt++) {
    int ln = wn + nt * 16 + r16;
    float bv = bias[n0 + ln];
    #pragma unroll
    for (int mt = 0; mt < 4; mt++)
      #pragma unroll
      for (int rr = 0; rr < 4; rr++) {
        int lm = wm + mt * 16 + quad * 4 + rr;
        unsigned short hv = f2b((acc[mt][nt][rr] + bv) * scale);
        if (mode == 2) smem[ln * 136 + lm] = hv;   // transposed: [n][m]
        else           smem[lm * 136 + ln] = hv;   // [m][n]
      }
  }
  __syncthreads();
  int rrow = t >> 1, half = t & 1;
  const unsigned short* src = smem + rrow * 136 + half * 64;
  if (mode == 2) {
    int b = m0 >> 11, s0 = m0 & 2047;
    int gn = n0 + rrow, h = gn >> 6, d = gn & 63;
    unsigned short* dst = outb + ((size_t)(b * 16 + h) * 64 + d) * 2048 + s0 + half * 64;
    #pragma unroll
    for (int j = 0; j < 8; j++) *(int4*)(dst + j * 8) = *(const int4*)(src + j * 8);
  } else {
    int gm = m0 + rrow, b = gm >> 11, s = gm & 2047;
    int h = (n0 + half * 64) >> 6;
    unsigned short* dst = outb + ((size_t)(b * 16 + h) * 2048 + s) * 64;
    #pragma unroll
    for (int j = 0; j < 8; j++) *(int4*)(dst + j * 8) = *(const int4*)(src + j * 8);
  }
}

// ---- out projection: Y(4096x1024) fp32 = xb(bf16) @ Wot^T + bo, 64x128 tile ----
// flat grid 512: m_t = f&63 (XCD key), n_t = f>>6. 8 n-blocks per A-panel -> same XCD.
__global__ __launch_bounds__(256) void k_gemm_o(const unsigned short* __restrict__ Ab,
                                                const unsigned short* __restrict__ Bt,
                                                const float* __restrict__ bias,
                                                float* __restrict__ outf) {
  __shared__ __align__(16) unsigned short As[64 * 64];
  __shared__ __align__(16) unsigned short Bs[128 * 64];
  int t = threadIdx.x;
  int wave = t >> 6, lane = t & 63;
  int r16 = lane & 15, quad = lane >> 4;
  int f = blockIdx.x;
  int m0 = (f & 63) * 64, n0 = (f >> 6) * 128;
  int wm = (wave & 1) * 32, wn = (wave >> 1) * 64;
  f32x4 acc[2][4] = {};

  for (int k0 = 0; k0 < 1024; k0 += 64) {
    __syncthreads();
    #pragma unroll
    for (int i = 0; i < 2; i++) {
      int row = wave * 16 + i * 8 + (lane >> 3);
      int sw = (((lane & 7) ^ (row & 7))) * 8;
      async16(Ab + (size_t)(m0 + row) * 1024 + k0 + sw, &As[(wave * 16 + i * 8) * 64]);
    }
    #pragma unroll
    for (int i = 0; i < 4; i++) {
      int row = wave * 32 + i * 8 + (lane >> 3);
      int sw = (((lane & 7) ^ (row & 7))) * 8;
      async16(Bt + (size_t)(n0 + row) * 1024 + k0 + sw, &Bs[(wave * 32 + i * 8) * 64]);
    }
    __syncthreads();
    #pragma unroll
    for (int kk2 = 0; kk2 < 2; kk2++) {
      int gq = quad + kk2 * 4;
      bf16x8 av[2], bv[4];
      #pragma unroll
      for (int mt = 0; mt < 2; mt++) {
        int lm = wm + mt * 16 + r16;
        av[mt] = ld8(&As[lm * 64 + (gq ^ (lm & 7)) * 8]);
      }
      #pragma unroll
      for (int nt = 0; nt < 4; nt++) {
        int ln = wn + nt * 16 + r16;
        bv[nt] = ld8(&Bs[ln * 64 + (gq ^ (ln & 7)) * 8]);
      }
      #pragma unroll
      for (int mt = 0; mt < 2; mt++)
        #pragma unroll
        for (int nt = 0; nt < 4; nt++)
          acc[mt][nt] = __builtin_amdgcn_mfma_f32_16x16x32_bf16(av[mt], bv[nt], acc[mt][nt], 0, 0, 0);
    }
  }
  #pragma unroll
  for (int nt = 0; nt < 4; nt++) {
    int gn = n0 + wn + nt * 16 + r16;
    float bv = bias[gn];
    #pragma unroll
    for (int mt = 0; mt < 2; mt++)
      #pragma unroll
      for (int rr = 0; rr < 4; rr++) {
        int gm = m0 + wm + mt * 16 + quad * 4 + rr;
        outf[(size_t)gm * 1024 + gn] = acc[mt][nt][rr] + bv;
      }
  }
}

// ---- flash attention: q-tile 128, k-tile 64 ----
// flat grid 512: bh = f&31 (XCD key), qt = f>>5. 16 q-blocks per (b,h) -> same XCD
// -> K/V panels (512 KB) L2-resident.
// Bias for iter k+1 is prefetched into registers during iter k's softmax/PV
// (T14 async-split): hides the ~900-cycle L3-miss latency of the 536 MB stream.
__global__ __launch_bounds__(256) void k_attn(const unsigned short* __restrict__ qh,
                                              const unsigned short* __restrict__ kh,
                                              const unsigned short* __restrict__ vt,
                                              const float* __restrict__ bias,
                                              const int* __restrict__ mask,
                                              unsigned short* __restrict__ xb) {
  __shared__ __align__(16) unsigned short Ks[64 * 64];   // swizzled [key][d]
  __shared__ __align__(16) unsigned short Vs[64 * 64];   // swizzled [d][key]
  __shared__ __align__(16) unsigned short Ps[128 * 72];  // padded   [q][key]
  __shared__ float kmb[64];
  int t = threadIdx.x;
  int wave = t >> 6, lane = t & 63;
  int r16 = lane & 15, quad = lane >> 4, quad8 = quad * 8;
  int w32 = wave * 32;
  int f = blockIdx.x;
  int bh = f & 31, q0 = (f >> 5) * 128;
  int b = bh >> 4, h = bh & 15;
  const unsigned short* kbase = kh + (size_t)bh * 2048 * 64;
  const unsigned short* vbase = vt + (size_t)bh * 64 * 2048;
  const float* bbase = bias + (size_t)bh * 2048 * 2048 + (size_t)q0 * 2048;

  // Q fragments in registers for the whole K-loop (2 m-frags x 2 k-halves)
  bf16x8 qf[2][2];
  #pragma unroll
  for (int mt = 0; mt < 2; mt++) {
    const unsigned short* qrow = qh + (size_t)bh * 2048 * 64 + (size_t)(q0 + w32 + mt * 16 + r16) * 64;
    qf[mt][0] = ld8(qrow + quad8);
    qf[mt][1] = ld8(qrow + 32 + quad8);
  }
  const u16x8 onesu = {0x3F80, 0x3F80, 0x3F80, 0x3F80, 0x3F80, 0x3F80, 0x3F80, 0x3F80};
  const bf16x8 ones = __builtin_bit_cast(bf16x8, onesu);

  f32x4 o[2][4] = {};
  f32x4 accl[2] = {};  // row-sums l via MFMA vs ones, alpha-rescaled like o
  float mrow[2][4] = {{-1e38f, -1e38f, -1e38f, -1e38f}, {-1e38f, -1e38f, -1e38f, -1e38f}};

  // bias prefetch registers for the current k-tile (issued one iter ahead)
  float bpf[2][4][4];
  #pragma unroll
  for (int mt = 0; mt < 2; mt++)
    #pragma unroll
    for (int nt = 0; nt < 4; nt++)
      #pragma unroll
      for (int rr = 0; rr < 4; rr++)
        bpf[mt][nt][rr] = bbase[(size_t)(w32 + mt * 16 + quad * 4 + rr) * 2048 + nt * 16 + r16];

  for (int k0 = 0; k0 < 2048; k0 += 64) {
    __syncthreads();  // prev iter frag reads done
    #pragma unroll
    for (int j = 0; j < 2; j++) {  // stage K and V^T via async, swizzled gather
      int row = wave * 16 + j * 8 + (lane >> 3);
      int sw = (((lane & 7) ^ (row & 7))) * 8;
      async16(kbase + (size_t)(k0 + row) * 64 + sw, &Ks[(wave * 16 + j * 8) * 64]);
      async16(vbase + (size_t)row * 2048 + k0 + sw, &Vs[(wave * 16 + j * 8) * 64]);
    }
    if (t < 64) kmb[t] = (mask[b * 2048 + k0 + t] == 0) ? 1.0f : 0.0f;
    __syncthreads();

    // S = Q K^T  (Q pre-scaled by 1/8 in projection)
    f32x4 sc[2][4] = {};
    #pragma unroll
    for (int kk2 = 0; kk2 < 2; kk2++) {
      bf16x8 kf[4];
      int gq = quad + kk2 * 4;
      #pragma unroll
      for (int nt = 0; nt < 4; nt++) {
        int ln = nt * 16 + r16;
        kf[nt] = ld8(&Ks[ln * 64 + (gq ^ (ln & 7)) * 8]);
      }
      #pragma unroll
      for (int mt = 0; mt < 2; mt++)
        #pragma unroll
        for (int nt = 0; nt < 4; nt++)
          sc[mt][nt] = __builtin_amdgcn_mfma_f32_16x16x32_bf16(qf[mt][kk2], kf[nt], sc[mt][nt], 0, 0, 0);
    }
    // key-mask -> NEG, then + bias (reference order); bias comes from prefetch regs
    #pragma unroll
    for (int mt = 0; mt < 2; mt++)
      #pragma unroll
      for (int nt = 0; nt < 4; nt++) {
        float km = kmb[nt * 16 + r16];
        #pragma unroll
        for (int rr = 0; rr < 4; rr++)
          sc[mt][nt][rr] = ((km > 0.5f) ? NEGV : sc[mt][nt][rr]) + bpf[mt][nt][rr];
      }
    // issue next k-tile's bias loads now; they complete under softmax+Ps+PV
    {
      int kn = (k0 + 64) & 2047;  // last iter wraps to 0 (harmless, discarded)
      #pragma unroll
      for (int mt = 0; mt < 2; mt++)
        #pragma unroll
        for (int nt = 0; nt < 4; nt++)
          #pragma unroll
          for (int rr = 0; rr < 4; rr++)
            bpf[mt][nt][rr] = bbase[(size_t)(w32 + mt * 16 + quad * 4 + rr) * 2048 + kn + nt * 16 + r16];
    }
    // online softmax: row-max via shuffles; row-sum free via ones-MFMA
    float arow[2][4];
    #pragma unroll
    for (int mt = 0; mt < 2; mt++)
      #pragma unroll
      for (int rr = 0; rr < 4; rr++) {
        float mx = fmaxf(fmaxf(sc[mt][0][rr], sc[mt][1][rr]), fmaxf(sc[mt][2][rr], sc[mt][3][rr]));
        #pragma unroll
        for (int off = 1; off < 16; off <<= 1) mx = fmaxf(mx, __shfl_xor(mx, off));
        float mn = fmaxf(mrow[mt][rr], mx);
        arow[mt][rr] = __expf(mrow[mt][rr] - mn);
        mrow[mt][rr] = mn;
        #pragma unroll
        for (int nt = 0; nt < 4; nt++) sc[mt][nt][rr] = __expf(sc[mt][nt][rr] - mn);
      }
    // P: C-layout -> A-layout via LDS (wave-private rows, no barrier needed)
    #pragma unroll
    for (int mt = 0; mt < 2; mt++)
      #pragma unroll
      for (int nt = 0; nt < 4; nt++)
        #pragma unroll
        for (int rr = 0; rr < 4; rr++)
          Ps[(w32 + mt * 16 + quad * 4 + rr) * 72 + nt * 16 + r16] = f2b(sc[mt][nt][rr]);
    #pragma unroll
    for (int mt = 0; mt < 2; mt++)
      #pragma unroll
      for (int rr = 0; rr < 4; rr++) {
        accl[mt][rr] *= arow[mt][rr];
        #pragma unroll
        for (int nt = 0; nt < 4; nt++) o[mt][nt][rr] *= arow[mt][rr];
      }
    // O += P V ; l += P @ 1
    #pragma unroll
    for (int kk2 = 0; kk2 < 2; kk2++) {
      bf16x8 vf[4];
      int gq = quad + kk2 * 4;
      #pragma unroll
      for (int nt = 0; nt < 4; nt++) {
        int ln = nt * 16 + r16;
        vf[nt] = ld8(&Vs[ln * 64 + (gq ^ (ln & 7)) * 8]);
      }
      #pragma unroll
      for (int mt = 0; mt < 2; mt++) {
        bf16x8 a = ld8(&Ps[(w32 + mt * 16 + r16) * 72 + kk2 * 32 + quad8]);
        accl[mt] = __builtin_amdgcn_mfma_f32_16x16x32_bf16(a, ones, accl[mt], 0, 0, 0);
        #pragma unroll
        for (int nt = 0; nt < 4; nt++)
          o[mt][nt] = __builtin_amdgcn_mfma_f32_16x16x32_bf16(a, vf[nt], o[mt][nt], 0, 0, 0);
      }
    }
  }

  #pragma unroll
  for (int mt = 0; mt < 2; mt++) {
    float inv[4];
    #pragma unroll
    for (int rr = 0; rr < 4; rr++) {
      int gq = q0 + w32 + mt * 16 + quad * 4 + rr;
      float qm = (mask[b * 2048 + gq] != 0) ? 1.0f : 0.0f;
      inv[rr] = qm / accl[mt][rr];
    }
    #pragma unroll
    for (int nt = 0; nt < 4; nt++)
      #pragma unroll
      for (int rr = 0; rr < 4; rr++) {
        int gq = q0 + w32 + mt * 16 + quad * 4 + rr;
        xb[(size_t)(b * 2048 + gq) * 1024 + h * 64 + nt * 16 + r16] = f2b(o[mt][nt][rr] * inv[rr]);
      }
  }
}

extern "C" void kernel_launch(void* const* d_in, const int* in_sizes, int n_in,
                              void* d_out, int out_size, void* d_ws, size_t ws_size,
                              hipStream_t stream) {
  const float* q = (const float*)d_in[0];
  const float* k = (const float*)d_in[1];
  const float* v = (const float*)d_in[2];
  const float* attn_bias = (const float*)d_in[3];
  const int* mask = (const int*)d_in[4];
  const float* Wq = (const float*)d_in[5];
  const float* bq = (const float*)d_in[6];
  const float* Wk = (const float*)d_in[7];
  const float* bk = (const float*)d_in[8];
  const float* Wv = (const float*)d_in[9];
  const float* bv = (const float*)d_in[10];
  const float* Wo = (const float*)d_in[11];
  const float* bo = (const float*)d_in[12];

  char* ws = (char*)d_ws;
  const size_t MB = 1u << 20;
  unsigned short* Wqt = (unsigned short*)(ws + 0 * MB);
  unsigned short* Wkt = (unsigned short*)(ws + 2 * MB);
  unsigned short* Wvt = (unsigned short*)(ws + 4 * MB);
  unsigned short* Wot = (unsigned short*)(ws + 6 * MB);
  unsigned short* qhb = (unsigned short*)(ws + 8 * MB);
  unsigned short* khb = (unsigned short*)(ws + 16 * MB);
  unsigned short* vtb = (unsigned short*)(ws + 24 * MB);
  unsigned short* xbb = (unsigned short*)(ws + 32 * MB);
  unsigned short* qcb = (unsigned short*)(ws + 40 * MB);
  unsigned short* kcb = (unsigned short*)(ws + 48 * MB);
  unsigned short* vcb = (unsigned short*)(ws + 56 * MB);

  k_cvt<<<dim3(2048, 1, 3), 256, 0, stream>>>(q, k, v, qcb, kcb, vcb);

  k_wtrans<<<dim3(32, 32, 4), dim3(32, 8), 0, stream>>>(Wq, Wk, Wv, Wo, Wqt, Wkt, Wvt, Wot);

  k_gemm_qkv<<<768, 256, 0, stream>>>(qcb, kcb, vcb, Wqt, Wkt, Wvt, bq, bk, bv,
                                      qhb, khb, vtb);

  k_attn<<<512, 256, 0, stream>>>(qhb, khb, vtb, attn_bias, mask, xbb);

  k_gemm_o<<<512, 256, 0, stream>>>(xbb, Wot, bo, (float*)d_out);
}

// Round 3
// 815.786 us; speedup vs baseline: 1.0847x; 1.0658x over previous
//
#include <hip/hip_runtime.h>

// MHA: B=2, S=2048, HID=1024, H=16, DK=64. SCALE=1/8, NEG=-1e9.
// Pipeline: [cvt qkv fp32->bf16] + [wtrans z=4] -> [fused qkv gemm, 128x128]
//           -> [mask scan (into dead qcb region)] + [zero xb]
//           -> [flash attn, q-row COMPACTED, K/V dbuf, bias reg-prefetch]
//           -> [out gemm 64x128].
// Masked q-rows (~50%) produce output rows == bo exactly (reference multiplies x by
// q-mask before Wo). We compact unmasked q-rows per batch (row-granular: bias loads
// stay 64B-coalesced; key dim stays dense) -> bias HBM 536->~268 MB, attn work -50%.
// Masked rows: xb pre-zeroed -> out gemm yields bo.
// WORKSPACE IS EXACTLY 64 MiB: idx/cnt live inside qcb's region (dead after the
// qkv GEMM; k_scan launches after it). Round-2 crash root-cause: idx was at
// ws+64MiB -> OOB.
// bf16 MFMA 16x16x32; A[m=lane&15][k=quad*8+j], B^T[n=lane&15][k=quad*8+j],
// C/D col=lane&15, row=quad*4+reg.
// LDS tiles: unpadded 64-u16 rows, XOR group swizzle (g ^= row&7) -> conflict-free
// frag reads AND global_load_lds-compatible (swizzle applied to global address).
// Flat grids, XCD-aware decode (XCD = wgid % 8): blocks sharing an A-panel (GEMMs)
// or a K/V panel (attn) co-reside on one XCD's L2.

typedef __bf16 bf16x8 __attribute__((ext_vector_type(8)));
typedef float f32x4 __attribute__((ext_vector_type(4)));
typedef unsigned short u16x8 __attribute__((ext_vector_type(8)));

#define NEGV (-1000000000.0f)

typedef __attribute__((address_space(3))) unsigned int lds_u32;
typedef const __attribute__((address_space(1))) unsigned int glb_u32;

static __device__ __forceinline__ void async16(const void* g, void* l) {
  __builtin_amdgcn_global_load_lds((glb_u32*)g, (lds_u32*)l, 16, 0, 0);
}

static __device__ __forceinline__ unsigned short f2b(float f) {
  unsigned int u = __float_as_uint(f);
  return (unsigned short)((u + 0x7FFFu + ((u >> 16) & 1u)) >> 16);
}

static __device__ __forceinline__ bf16x8 ld8(const unsigned short* p) {
  return __builtin_bit_cast(bf16x8, *(const u16x8*)p);
}

// ---- elementwise fp32 -> bf16 for q,k,v ----
__global__ __launch_bounds__(256) void k_cvt(const float* __restrict__ A0, const float* __restrict__ A1,
                                             const float* __restrict__ A2,
                                             unsigned short* __restrict__ O0, unsigned short* __restrict__ O1,
                                             unsigned short* __restrict__ O2) {
  const float* A = (blockIdx.z == 0) ? A0 : (blockIdx.z == 1) ? A1 : A2;
  unsigned short* O = (blockIdx.z == 0) ? O0 : (blockIdx.z == 1) ? O1 : O2;
  size_t i = ((size_t)blockIdx.x * 256 + threadIdx.x) * 8;
  float4 f0 = *(const float4*)(A + i);
  float4 f1 = *(const float4*)(A + i + 4);
  u16x8 h;
  h[0] = f2b(f0.x); h[1] = f2b(f0.y); h[2] = f2b(f0.z); h[3] = f2b(f0.w);
  h[4] = f2b(f1.x); h[5] = f2b(f1.y); h[6] = f2b(f1.z); h[7] = f2b(f1.w);
  *(u16x8*)(O + i) = h;
}

// ---- zero xb (masked q-rows must contribute exactly 0 to out gemm) ----
__global__ __launch_bounds__(256) void k_zero(unsigned short* __restrict__ p) {
  size_t i = ((size_t)blockIdx.x * 256 + threadIdx.x) * 8;
  u16x8 z = {0, 0, 0, 0, 0, 0, 0, 0};
  *(u16x8*)(p + i) = z;
}

// ---- per-batch compaction of unmasked q-rows: idx[b][j]=s (ascending), cnt[b] ----
__global__ __launch_bounds__(64) void k_scan(const int* __restrict__ mask,
                                             int* __restrict__ idx, int* __restrict__ cnt) {
  int b = blockIdx.x;
  int t = threadIdx.x;
  int m[32];
  int c = 0;
  #pragma unroll
  for (int j = 0; j < 32; j++) {
    m[j] = (mask[b * 2048 + t * 32 + j] != 0) ? 1 : 0;
    c += m[j];
  }
  int inc = c;
  #pragma unroll
  for (int off = 1; off < 64; off <<= 1) {
    int v = __shfl_up(inc, off);
    if (t >= off) inc += v;
  }
  int pos = inc - c;
  #pragma unroll
  for (int j = 0; j < 32; j++) {
    if (m[j]) { idx[b * 2048 + pos] = t * 32 + j; pos++; }
  }
  if (t == 63) cnt[b] = inc;
}

// ---- transpose 1024x1024 fp32 W -> bf16 W^T (N x K), batched over z ----
__global__ __launch_bounds__(256) void k_wtrans(const float* __restrict__ W0, const float* __restrict__ W1,
                                                const float* __restrict__ W2, const float* __restrict__ W3,
                                                unsigned short* __restrict__ T0, unsigned short* __restrict__ T1,
                                                unsigned short* __restrict__ T2, unsigned short* __restrict__ T3) {
  const float* W = (blockIdx.z == 0) ? W0 : (blockIdx.z == 1) ? W1 : (blockIdx.z == 2) ? W2 : W3;
  unsigned short* Wt = (blockIdx.z == 0) ? T0 : (blockIdx.z == 1) ? T1 : (blockIdx.z == 2) ? T2 : T3;
  __shared__ float tile[32][33];
  int k0 = blockIdx.x * 32, n0 = blockIdx.y * 32;
  int tx = threadIdx.x, ty = threadIdx.y;
  #pragma unroll
  for (int i = 0; i < 32; i += 8)
    tile[ty + i][tx] = W[(size_t)(k0 + ty + i) * 1024 + n0 + tx];
  __syncthreads();
  #pragma unroll
  for (int i = 0; i < 32; i += 8)
    Wt[(size_t)(n0 + ty + i) * 1024 + k0 + tx] = f2b(tile[tx][ty + i]);
}

// ---- fused QKV GEMM: Y(4096x1024) = A(bf16) @ Wt^T + bias, 128x128 tile ----
__global__ __launch_bounds__(256) void k_gemm_qkv(
    const unsigned short* __restrict__ A0, const unsigned short* __restrict__ A1,
    const unsigned short* __restrict__ A2,
    const unsigned short* __restrict__ W0, const unsigned short* __restrict__ W1,
    const unsigned short* __restrict__ W2,
    const float* __restrict__ b0, const float* __restrict__ b1, const float* __restrict__ b2,
    unsigned short* __restrict__ o0, unsigned short* __restrict__ o1, unsigned short* __restrict__ o2) {
  int f = blockIdx.x;
  int mode = f >> 8;
  int r = f & 255;
  int m0 = (r & 31) * 128, n0 = (r >> 5) * 128;
  const unsigned short* Ab = (mode == 0) ? A0 : (mode == 1) ? A1 : A2;
  const unsigned short* Bt = (mode == 0) ? W0 : (mode == 1) ? W1 : W2;
  const float* bias = (mode == 0) ? b0 : (mode == 1) ? b1 : b2;
  unsigned short* outb = (mode == 0) ? o0 : (mode == 1) ? o1 : o2;

  __shared__ __align__(16) unsigned short smem[128 * 136];  // stage + epilogue union
  unsigned short* As = smem;             // [128][64], swizzled groups
  unsigned short* Bs = smem + 128 * 64;  // [128][64], swizzled groups
  int t = threadIdx.x;
  int wave = t >> 6, lane = t & 63;
  int r16 = lane & 15, quad = lane >> 4;
  int wm = (wave >> 1) * 64, wn = (wave & 1) * 64;
  f32x4 acc[4][4] = {};

  for (int k0 = 0; k0 < 1024; k0 += 64) {
    __syncthreads();
    #pragma unroll
    for (int i = 0; i < 4; i++) {  // both operands via async copy, swizzled gather
      int row = wave * 32 + i * 8 + (lane >> 3);
      int sw = (((lane & 7) ^ (row & 7))) * 8;
      async16(Ab + (size_t)(m0 + row) * 1024 + k0 + sw, &As[(wave * 32 + i * 8) * 64]);
      async16(Bt + (size_t)(n0 + row) * 1024 + k0 + sw, &Bs[(wave * 32 + i * 8) * 64]);
    }
    __syncthreads();
    #pragma unroll
    for (int kk2 = 0; kk2 < 2; kk2++) {
      bf16x8 av[4], bv[4];
      int gq = quad + kk2 * 4;
      #pragma unroll
      for (int mt = 0; mt < 4; mt++) {
        int lm = wm + mt * 16 + r16;
        av[mt] = ld8(&As[lm * 64 + (gq ^ (lm & 7)) * 8]);
      }
      #pragma unroll
      for (int nt = 0; nt < 4; nt++) {
        int ln = wn + nt * 16 + r16;
        bv[nt] = ld8(&Bs[ln * 64 + (gq ^ (ln & 7)) * 8]);
      }
      #pragma unroll
      for (int mt = 0; mt < 4; mt++)
        #pragma unroll
        for (int nt = 0; nt < 4; nt++)
          acc[mt][nt] = __builtin_amdgcn_mfma_f32_16x16x32_bf16(av[mt], bv[nt], acc[mt][nt], 0, 0, 0);
    }
  }

  __syncthreads();  // staging reads done; smem becomes epilogue buffer [128][136]
  float scale = (mode == 0) ? 0.125f : 1.0f;
  #pragma unroll
  for (int nt = 0; nt < 4; nt++) {
    int ln = wn + nt * 16 + r16;
    float bv = bias[n0 + ln];
    #pragma unroll
    for (int mt = 0; mt < 4; mt++)
      #pragma unroll
      for (int rr = 0; rr < 4; rr++) {
        int lm = wm + mt * 16 + quad * 4 + rr;
        unsigned short hv = f2b((acc[mt][nt][rr] + bv) * scale);
        if (mode == 2) smem[ln * 136 + lm] = hv;   // transposed: [n][m]
        else           smem[lm * 136 + ln] = hv;   // [m][n]
      }
  }
  __syncthreads();
  int rrow = t >> 1, half = t & 1;
  const unsigned short* src = smem + rrow * 136 + half * 64;
  if (mode == 2) {
    int b = m0 >> 11, s0 = m0 & 2047;
    int gn = n0 + rrow, h = gn >> 6, d = gn & 63;
    unsigned short* dst = outb + ((size_t)(b * 16 + h) * 64 + d) * 2048 + s0 + half * 64;
    #pragma unroll
    for (int j = 0; j < 8; j++) *(int4*)(dst + j * 8) = *(const int4*)(src + j * 8);
  } else {
    int gm = m0 + rrow, b = gm >> 11, s = gm & 2047;
    int h = (n0 + half * 64) >> 6;
    unsigned short* dst = outb + ((size_t)(b * 16 + h) * 2048 + s) * 64;
    #pragma unroll
    for (int j = 0; j < 8; j++) *(int4*)(dst + j * 8) = *(const int4*)(src + j * 8);
  }
}

// ---- out projection: Y(4096x1024) fp32 = xb(bf16) @ Wot^T + bo, 64x128 tile ----
__global__ __launch_bounds__(256) void k_gemm_o(const unsigned short* __restrict__ Ab,
                                                const unsigned short* __restrict__ Bt,
                                                const float* __restrict__ bias,
                                                float* __restrict__ outf) {
  __shared__ __align__(16) unsigned short As[64 * 64];
  __shared__ __align__(16) unsigned short Bs[128 * 64];
  int t = threadIdx.x;
  int wave = t >> 6, lane = t & 63;
  int r16 = lane & 15, quad = lane >> 4;
  int f = blockIdx.x;
  int m0 = (f & 63) * 64, n0 = (f >> 6) * 128;
  int wm = (wave & 1) * 32, wn = (wave >> 1) * 64;
  f32x4 acc[2][4] = {};

  for (int k0 = 0; k0 < 1024; k0 += 64) {
    __syncthreads();
    #pragma unroll
    for (int i = 0; i < 2; i++) {
      int row = wave * 16 + i * 8 + (lane >> 3);
      int sw = (((lane & 7) ^ (row & 7))) * 8;
      async16(Ab + (size_t)(m0 + row) * 1024 + k0 + sw, &As[(wave * 16 + i * 8) * 64]);
    }
    #pragma unroll
    for (int i = 0; i < 4; i++) {
      int row = wave * 32 + i * 8 + (lane >> 3);
      int sw = (((lane & 7) ^ (row & 7))) * 8;
      async16(Bt + (size_t)(n0 + row) * 1024 + k0 + sw, &Bs[(wave * 32 + i * 8) * 64]);
    }
    __syncthreads();
    #pragma unroll
    for (int kk2 = 0; kk2 < 2; kk2++) {
      int gq = quad + kk2 * 4;
      bf16x8 av[2], bv[4];
      #pragma unroll
      for (int mt = 0; mt < 2; mt++) {
        int lm = wm + mt * 16 + r16;
        av[mt] = ld8(&As[lm * 64 + (gq ^ (lm & 7)) * 8]);
      }
      #pragma unroll
      for (int nt = 0; nt < 4; nt++) {
        int ln = wn + nt * 16 + r16;
        bv[nt] = ld8(&Bs[ln * 64 + (gq ^ (ln & 7)) * 8]);
      }
      #pragma unroll
      for (int mt = 0; mt < 2; mt++)
        #pragma unroll
        for (int nt = 0; nt < 4; nt++)
          acc[mt][nt] = __builtin_amdgcn_mfma_f32_16x16x32_bf16(av[mt], bv[nt], acc[mt][nt], 0, 0, 0);
    }
  }
  #pragma unroll
  for (int nt = 0; nt < 4; nt++) {
    int gn = n0 + wn + nt * 16 + r16;
    float bv = bias[gn];
    #pragma unroll
    for (int mt = 0; mt < 2; mt++)
      #pragma unroll
      for (int rr = 0; rr < 4; rr++) {
        int gm = m0 + wm + mt * 16 + quad * 4 + rr;
        outf[(size_t)gm * 1024 + gn] = acc[mt][nt][rr] + bv;
      }
  }
}

// ---- flash attention on COMPACTED q-rows: q-tile 128, k-tile 64, K/V dbuf ----
// flat grid 512: bh = f&31 (XCD key), qt = f>>5; block active iff qt*128 < cnt[b].
// Bias rows gathered via idx (row-granular -> 64B-coalesced); bias for iter k+1
// prefetched into regs during iter k. STAGE(next) -> compute(cur) -> barrier hides
// K/V staging latency under compute (2-phase dbuf).
__global__ __launch_bounds__(256) void k_attn(const unsigned short* __restrict__ qh,
                                              const unsigned short* __restrict__ kh,
                                              const unsigned short* __restrict__ vt,
                                              const float* __restrict__ bias,
                                              const int* __restrict__ mask,
                                              const int* __restrict__ idx,
                                              const int* __restrict__ cnt,
                                              unsigned short* __restrict__ xb) {
  __shared__ __align__(16) unsigned short Ks[2][64 * 64];  // swizzled [key][d]
  __shared__ __align__(16) unsigned short Vs[2][64 * 64];  // swizzled [d][key]
  __shared__ __align__(16) unsigned short Ps[128 * 72];    // padded   [q][key]
  __shared__ float kmb[2][64];
  __shared__ int idxL[128];
  int t = threadIdx.x;
  int wave = t >> 6, lane = t & 63;
  int r16 = lane & 15, quad = lane >> 4, quad8 = quad * 8;
  int w32 = wave * 32;
  int f = blockIdx.x;
  int bh = f & 31, qt = f >> 5;
  int b = bh >> 4, h = bh & 15;
  int cb = cnt[b];
  int q0 = qt * 128;
  if (q0 >= cb) return;

  if (t < 128) idxL[t] = (q0 + t < cb) ? idx[b * 2048 + q0 + t] : idx[b * 2048];
  const unsigned short* kbase = kh + (size_t)bh * 2048 * 64;
  const unsigned short* vbase = vt + (size_t)bh * 64 * 2048;

#define STAGE_KV(bufi, kt_) do {                                                     \
    int k0s = (kt_) * 64;                                                            \
    _Pragma("unroll")                                                                \
    for (int j = 0; j < 2; j++) {                                                    \
      int row = wave * 16 + j * 8 + (lane >> 3);                                     \
      int sw = (((lane & 7) ^ (row & 7))) * 8;                                       \
      async16(kbase + (size_t)(k0s + row) * 64 + sw, &Ks[bufi][(wave * 16 + j * 8) * 64]); \
      async16(vbase + (size_t)row * 2048 + k0s + sw, &Vs[bufi][(wave * 16 + j * 8) * 64]); \
    }                                                                                \
    if (t < 64) kmb[bufi][t] = (mask[b * 2048 + k0s + t] == 0) ? 1.0f : 0.0f;        \
  } while (0)

  STAGE_KV(0, 0);
  __syncthreads();  // idxL visible; buf0 staging drained (vmcnt(0) before barrier)

  // per-lane compact-row -> original-s maps (registers, read once from LDS)
  int sm[2][4];    // C-layout rows (mt, rr): w32 + mt*16 + quad*4 + rr
  int vm[2][4];    // validity (beyond-cnt tail rows compute garbage, never written)
  int boff[2][4];  // bias element offset of row start
  #pragma unroll
  for (int mt = 0; mt < 2; mt++)
    #pragma unroll
    for (int rr = 0; rr < 4; rr++) {
      int j = w32 + mt * 16 + quad * 4 + rr;
      sm[mt][rr] = idxL[j];
      vm[mt][rr] = (q0 + j) < cb;
      boff[mt][rr] = (bh * 2048 + sm[mt][rr]) * 2048;
    }
  // Q fragments gathered by original row (A-layout rows: w32 + mt*16 + r16)
  bf16x8 qf[2][2];
  #pragma unroll
  for (int mt = 0; mt < 2; mt++) {
    int sqr = idxL[w32 + mt * 16 + r16];
    const unsigned short* qrow = qh + ((size_t)bh * 2048 + sqr) * 64;
    qf[mt][0] = ld8(qrow + quad8);
    qf[mt][1] = ld8(qrow + 32 + quad8);
  }
  const u16x8 onesu = {0x3F80, 0x3F80, 0x3F80, 0x3F80, 0x3F80, 0x3F80, 0x3F80, 0x3F80};
  const bf16x8 ones = __builtin_bit_cast(bf16x8, onesu);

  f32x4 o[2][4] = {};
  f32x4 accl[2] = {};
  float mrow[2][4] = {{-1e38f, -1e38f, -1e38f, -1e38f}, {-1e38f, -1e38f, -1e38f, -1e38f}};

  // bias prefetch regs for current k-tile (gathered rows, dense cols)
  float bpf[2][4][4];
  #pragma unroll
  for (int mt = 0; mt < 2; mt++)
    #pragma unroll
    for (int nt = 0; nt < 4; nt++)
      #pragma unroll
      for (int rr = 0; rr < 4; rr++)
        bpf[mt][nt][rr] = bias[(size_t)(unsigned)boff[mt][rr] + nt * 16 + r16];

  int cur = 0;
  for (int kt = 0; kt < 32; kt++) {
    if (kt < 31) STAGE_KV(cur ^ 1, kt + 1);  // overlaps with this tile's compute

    // S = Q K^T  (Q pre-scaled by 1/8 in projection)
    f32x4 sc[2][4] = {};
    #pragma unroll
    for (int kk2 = 0; kk2 < 2; kk2++) {
      bf16x8 kf[4];
      int gq = quad + kk2 * 4;
      #pragma unroll
      for (int nt = 0; nt < 4; nt++) {
        int ln = nt * 16 + r16;
        kf[nt] = ld8(&Ks[cur][ln * 64 + (gq ^ (ln & 7)) * 8]);
      }
      #pragma unroll
      for (int mt = 0; mt < 2; mt++)
        #pragma unroll
        for (int nt = 0; nt < 4; nt++)
          sc[mt][nt] = __builtin_amdgcn_mfma_f32_16x16x32_bf16(qf[mt][kk2], kf[nt], sc[mt][nt], 0, 0, 0);
    }
    // key-mask -> NEG, then + bias (reference order); bias from prefetch regs
    #pragma unroll
    for (int mt = 0; mt < 2; mt++)
      #pragma unroll
      for (int nt = 0; nt < 4; nt++) {
        float km = kmb[cur][nt * 16 + r16];
        #pragma unroll
        for (int rr = 0; rr < 4; rr++)
          sc[mt][nt][rr] = ((km > 0.5f) ? NEGV : sc[mt][nt][rr]) + bpf[mt][nt][rr];
      }
    // issue next k-tile's bias loads; complete under softmax+Ps+PV
    {
      int kn = ((kt + 1) & 31) * 64;  // last iter wraps (harmless, discarded)
      #pragma unroll
      for (int mt = 0; mt < 2; mt++)
        #pragma unroll
        for (int nt = 0; nt < 4; nt++)
          #pragma unroll
          for (int rr = 0; rr < 4; rr++)
            bpf[mt][nt][rr] = bias[(size_t)(unsigned)boff[mt][rr] + kn + nt * 16 + r16];
    }
    // online softmax
    float arow[2][4];
    #pragma unroll
    for (int mt = 0; mt < 2; mt++)
      #pragma unroll
      for (int rr = 0; rr < 4; rr++) {
        float mx = fmaxf(fmaxf(sc[mt][0][rr], sc[mt][1][rr]), fmaxf(sc[mt][2][rr], sc[mt][3][rr]));
        #pragma unroll
        for (int off = 1; off < 16; off <<= 1) mx = fmaxf(mx, __shfl_xor(mx, off));
        float mn = fmaxf(mrow[mt][rr], mx);
        arow[mt][rr] = __expf(mrow[mt][rr] - mn);
        mrow[mt][rr] = mn;
        #pragma unroll
        for (int nt = 0; nt < 4; nt++) sc[mt][nt][rr] = __expf(sc[mt][nt][rr] - mn);
      }
    // P: C-layout -> A-layout via LDS (wave-private rows, no barrier needed)
    #pragma unroll
    for (int mt = 0; mt < 2; mt++)
      #pragma unroll
      for (int nt = 0; nt < 4; nt++)
        #pragma unroll
        for (int rr = 0; rr < 4; rr++)
          Ps[(w32 + mt * 16 + quad * 4 + rr) * 72 + nt * 16 + r16] = f2b(sc[mt][nt][rr]);
    #pragma unroll
    for (int mt = 0; mt < 2; mt++)
      #pragma unroll
      for (int rr = 0; rr < 4; rr++) {
        accl[mt][rr] *= arow[mt][rr];
        #pragma unroll
        for (int nt = 0; nt < 4; nt++) o[mt][nt][rr] *= arow[mt][rr];
      }
    // O += P V ; l += P @ 1
    #pragma unroll
    for (int kk2 = 0; kk2 < 2; kk2++) {
      bf16x8 vf[4];
      int gq = quad + kk2 * 4;
      #pragma unroll
      for (int nt = 0; nt < 4; nt++) {
        int ln = nt * 16 + r16;
        vf[nt] = ld8(&Vs[cur][ln * 64 + (gq ^ (ln & 7)) * 8]);
      }
      #pragma unroll
      for (int mt = 0; mt < 2; mt++) {
        bf16x8 a = ld8(&Ps[(w32 + mt * 16 + r16) * 72 + kk2 * 32 + quad8]);
        accl[mt] = __builtin_amdgcn_mfma_f32_16x16x32_bf16(a, ones, accl[mt], 0, 0, 0);
        #pragma unroll
        for (int nt = 0; nt < 4; nt++)
          o[mt][nt] = __builtin_amdgcn_mfma_f32_16x16x32_bf16(a, vf[nt], o[mt][nt], 0, 0, 0);
      }
    }
    __syncthreads();  // drains next-tile staging (overlapped) + syncs buffers
    cur ^= 1;
  }

  // scatter compacted rows back to original positions (all unmasked -> qm == 1)
  #pragma unroll
  for (int mt = 0; mt < 2; mt++)
    #pragma unroll
    for (int rr = 0; rr < 4; rr++) {
      if (!vm[mt][rr]) continue;
      float iv = 1.0f / accl[mt][rr];
      size_t base = ((size_t)(b * 2048 + sm[mt][rr])) * 1024 + h * 64;
      #pragma unroll
      for (int nt = 0; nt < 4; nt++)
        xb[base + nt * 16 + r16] = f2b(o[mt][nt][rr] * iv);
    }
#undef STAGE_KV
}

extern "C" void kernel_launch(void* const* d_in, const int* in_sizes, int n_in,
                              void* d_out, int out_size, void* d_ws, size_t ws_size,
                              hipStream_t stream) {
  const float* q = (const float*)d_in[0];
  const float* k = (const float*)d_in[1];
  const float* v = (const float*)d_in[2];
  const float* attn_bias = (const float*)d_in[3];
  const int* mask = (const int*)d_in[4];
  const float* Wq = (const float*)d_in[5];
  const float* bq = (const float*)d_in[6];
  const float* Wk = (const float*)d_in[7];
  const float* bk = (const float*)d_in[8];
  const float* Wv = (const float*)d_in[9];
  const float* bv = (const float*)d_in[10];
  const float* Wo = (const float*)d_in[11];
  const float* bo = (const float*)d_in[12];

  char* ws = (char*)d_ws;
  const size_t MB = 1u << 20;
  unsigned short* Wqt = (unsigned short*)(ws + 0 * MB);
  unsigned short* Wkt = (unsigned short*)(ws + 2 * MB);
  unsigned short* Wvt = (unsigned short*)(ws + 4 * MB);
  unsigned short* Wot = (unsigned short*)(ws + 6 * MB);
  unsigned short* qhb = (unsigned short*)(ws + 8 * MB);
  unsigned short* khb = (unsigned short*)(ws + 16 * MB);
  unsigned short* vtb = (unsigned short*)(ws + 24 * MB);
  unsigned short* xbb = (unsigned short*)(ws + 32 * MB);
  unsigned short* qcb = (unsigned short*)(ws + 40 * MB);
  unsigned short* kcb = (unsigned short*)(ws + 48 * MB);
  unsigned short* vcb = (unsigned short*)(ws + 56 * MB);
  // idx/cnt reuse qcb's region: dead after k_gemm_qkv, and k_scan runs after it.
  int* idxb = (int*)(ws + 40 * MB);
  int* cntb = (int*)(ws + 40 * MB + 16384);

  k_cvt<<<dim3(2048, 1, 3), 256, 0, stream>>>(q, k, v, qcb, kcb, vcb);

  k_wtrans<<<dim3(32, 32, 4), dim3(32, 8), 0, stream>>>(Wq, Wk, Wv, Wo, Wqt, Wkt, Wvt, Wot);

  k_gemm_qkv<<<768, 256, 0, stream>>>(qcb, kcb, vcb, Wqt, Wkt, Wvt, bq, bk, bv,
                                      qhb, khb, vtb);

  k_scan<<<2, 64, 0, stream>>>(mask, idxb, cntb);

  k_zero<<<2048, 256, 0, stream>>>(xbb);

  k_attn<<<512, 256, 0, stream>>>(qhb, khb, vtb, attn_bias, mask, idxb, cntb, xbb);

  k_gemm_o<<<512, 256, 0, stream>>>(xbb, Wot, bo, (float*)d_out);
}